// Round 27
// baseline (1110.333 us; speedup 1.0000x reference)
//
#include <hip/hip_runtime.h>
#include <hip/hip_bf16.h>
#include <hip/hip_fp16.h>
#include <math.h>
#include <stdint.h>

#define N_N 20000
#define E_E 320000
#define B_B 256
#define D_D 64
#define H_H 4
#define HC  256
#define SCALE_ 0.125f   // 1/sqrt(64)

struct h4v { __half x, y, z, w; };

__device__ __forceinline__ float sigmoidf_(float x) { return 1.0f / (1.0f + expf(-x)); }

__device__ __forceinline__ void atomicMaxF(float* addr, float val) {
    if (val >= 0.0f) atomicMax((int*)addr, __float_as_int(val));
    else             atomicMin((unsigned int*)addr, __float_as_uint(val));
}

// ---------------- Threefry2x32 (KAT-verified r5) ----------------------------
__device__ __forceinline__ void tf_round(uint32_t& x0, uint32_t& x1, int R) {
    x0 += x1; x1 = (x1 << R) | (x1 >> (32 - R)); x1 ^= x0;
}
__device__ void threefry2x32(uint32_t k0, uint32_t k1, uint32_t c0, uint32_t c1,
                             uint32_t& o0, uint32_t& o1) {
    const int rot[8] = {13, 15, 26, 6, 17, 29, 16, 24};
    uint32_t ks[3] = {k0, k1, k0 ^ k1 ^ 0x1BD11BDAu};
    uint32_t x0 = c0 + ks[0], x1 = c1 + ks[1];
#pragma unroll
    for (int g = 0; g < 5; ++g) {
        const int base = (g & 1) ? 4 : 0;
        tf_round(x0, x1, rot[base + 0]); tf_round(x0, x1, rot[base + 1]);
        tf_round(x0, x1, rot[base + 2]); tf_round(x0, x1, rot[base + 3]);
        x0 += ks[(g + 1) % 3]; x1 += ks[(g + 2) % 3] + (uint32_t)(g + 1);
    }
    o0 = x0; o1 = x1;
}

__device__ __forceinline__ float jax_n32(uint32_t bits) {
    float f = __uint_as_float((bits >> 9) | 0x3f800000u) - 1.0f;
    const float lo = -0x1.fffffep-1f;
    float u = 2.0f * f + lo;
    u = fmaxf(lo, u);
    return 1.41421356237f * erfinvf(u);
}

// eps: jax partitionable 32-bit = XOR fold of threefry output pair (r20 PASS)
__global__ void k_eps(float* __restrict__ eps) {
    int i = blockIdx.x * 256 + threadIdx.x;
    if (i >= 32768) return;
    uint32_t o0, o1;
    threefry2x32(0u, 42u, 0u, (uint32_t)i, o0, o1);
    eps[i] = jax_n32(o0 ^ o1);
}

// ---------------- CSR build (once; ei/eattr are layer-invariant) ------------
__global__ void k_hist(const int* __restrict__ ei, int* __restrict__ deg) {
    int e = blockIdx.x * 256 + threadIdx.x;
    if (e < E_E) atomicAdd(&deg[ei[E_E + e]], 1);
}

__global__ void k_scan(const int* __restrict__ deg, int* __restrict__ rowp) {
    __shared__ int part[1024];
    int t = threadIdx.x;
    int base = t * 20;
    int loc[20]; int s = 0;
#pragma unroll
    for (int i = 0; i < 20; i++) {
        int idx = base + i;
        int v = (idx < N_N) ? deg[idx] : 0;
        loc[i] = s; s += v;
    }
    part[t] = s; __syncthreads();
    for (int off = 1; off < 1024; off <<= 1) {
        int v = (t >= off) ? part[t - off] : 0;
        __syncthreads();
        part[t] += v;
        __syncthreads();
    }
    int excl = (t == 0) ? 0 : part[t - 1];
#pragma unroll
    for (int i = 0; i < 20; i++) {
        int idx = base + i;
        if (idx < N_N) rowp[idx] = excl + loc[i];
    }
    if (t == 1023) rowp[N_N] = part[1023];
}

// scatter dst-sorted copies: srcs, dsts, attr_s
__global__ void k_scatter(const int* __restrict__ ei, const float* __restrict__ eattr,
                          const int* __restrict__ rowp, int* __restrict__ cnt,
                          int* __restrict__ srcs, int* __restrict__ dsts,
                          float* __restrict__ attr_s) {
    int e = blockIdx.x * 256 + threadIdx.x;
    if (e >= E_E) return;
    int d = ei[E_E + e];
    int p = atomicAdd(&cnt[d], 1);
    int pos = rowp[d] + p;
    srcs[pos] = ei[e];
    dsts[pos] = d;
    float4 at = *(const float4*)(eattr + (size_t)e * 4);
    *(float4*)(attr_s + (size_t)pos * 4) = at;
}

// ---------------- fused projection (+BN of previous layer) ------------------
// single d-loop for Q,K,V (+skip on wave 0); hs transposed [64][8]
// q,k,v fp16 in transposed node layout: [n][chan(64)][head(4)]
__global__ void k_proj(const float* __restrict__ hin,
                       const float* __restrict__ Wq, const float* __restrict__ bq,
                       const float* __restrict__ Wk, const float* __restrict__ bk,
                       const float* __restrict__ Wv, const float* __restrict__ bv,
                       const float* __restrict__ Ws, const float* __restrict__ bs,
                       const float* __restrict__ bnstPrev,
                       const float* __restrict__ gam, const float* __restrict__ bet,
                       int useBN,
                       __half* __restrict__ qh, __half* __restrict__ kh,
                       __half* __restrict__ vh, float* __restrict__ xr) {
    __shared__ float hs[64][8];   // [d][row]
    const int i0 = blockIdx.x * 8;
    const int tid = threadIdx.x;
    for (int t = tid; t < 8 * 64; t += 256) {
        int r = t >> 6, d = t & 63;
        float v = hin[i0 * 64 + t];
        if (useBN) {
            float mu = bnstPrev[d] * (1.0f / N_N);
            float var = bnstPrev[64 + d] * (1.0f / N_N) - mu * mu;
            v = gam[d] * (v - mu) * rsqrtf(var + 1e-5f) + bet[d];
        }
        hs[d][r] = v;
    }
    __syncthreads();
    const int c = tid;
    const int co = (c & 63) * 4 + (c >> 6);   // transposed slot
    const bool doSkip = (c < 64);             // wave 0 only (no divergence)
    float aq[8], ak[8], av[8], as_[8];
    {
        float b0 = bq[c], b1 = bk[c], b2 = bv[c];
        float b3 = doSkip ? bs[c] : 0.0f;
#pragma unroll
        for (int r = 0; r < 8; r++) { aq[r] = b0; ak[r] = b1; av[r] = b2; as_[r] = b3; }
    }
    for (int d = 0; d < 64; d++) {
        float wq = Wq[d * 256 + c];
        float wk = Wk[d * 256 + c];
        float wv = Wv[d * 256 + c];
        float wsv = doSkip ? Ws[d * 64 + c] : 0.0f;
        const float4* hp = (const float4*)(&hs[d][0]);
        float4 hA = hp[0], hB = hp[1];
        float hr[8] = {hA.x, hA.y, hA.z, hA.w, hB.x, hB.y, hB.z, hB.w};
#pragma unroll
        for (int r = 0; r < 8; r++) {
            float hv = hr[r];
            aq[r] += hv * wq;
            ak[r] += hv * wk;
            av[r] += hv * wv;
            as_[r] += hv * wsv;
        }
    }
#pragma unroll
    for (int r = 0; r < 8; r++) {
        qh[(size_t)(i0 + r) * 256 + co] = __float2half(aq[r]);
        kh[(size_t)(i0 + r) * 256 + co] = __float2half(ak[r]);
        vh[(size_t)(i0 + r) * 256 + co] = __float2half(av[r]);
    }
    if (doSkip) {
#pragma unroll
        for (int r = 0; r < 8; r++) xr[(size_t)(i0 + r) * 64 + c] = as_[r];
    }
}

// ---------------- qwe[n][j*4+h] = sum_d q[n][h*64+d] * We[j][h*64+d] --------
__global__ void k_qwe(const __half* __restrict__ qh, const float* __restrict__ We,
                      float* __restrict__ qwe) {
    int t = blockIdx.x * 256 + threadIdx.x;
    if (t >= N_N * 16) return;
    int n = t >> 4, j = (t >> 2) & 3, h = t & 3;
    const __half* qp = qh + (size_t)n * 256 + h;
    const float* wp = We + j * 256 + h * 64;
    float s = 0.0f;
#pragma unroll 8
    for (int d = 0; d < 64; d++)
        s += __half2float(qp[d * 4]) * wp[d];
    qwe[t] = s;
}

// ---------------- edge pass (CSR order): qk dot + qwe term ------------------
__global__ void k_edge_alpha(const __half* __restrict__ qh, const __half* __restrict__ kh,
                             const float* __restrict__ attr_s, const float* __restrict__ qwe,
                             const int* __restrict__ srcs, const int* __restrict__ dsts,
                             float* __restrict__ alpha) {
    int tid = threadIdx.x;
    int ii = blockIdx.x * 16 + (tid >> 4);
    if (ii >= E_E) return;
    int lane = tid & 15;
    int src = srcs[ii], dst = dsts[ii];
    const h4v* qp = (const h4v*)(qh + (size_t)dst * 256 + lane * 16);
    const h4v* kp = (const h4v*)(kh + (size_t)src * 256 + lane * 16);
    float p0 = 0.0f, p1 = 0.0f, p2 = 0.0f, p3 = 0.0f;
#pragma unroll
    for (int i = 0; i < 4; i++) {
        h4v q4 = qp[i], k4 = kp[i];
        p0 += __half2float(q4.x) * __half2float(k4.x);
        p1 += __half2float(q4.y) * __half2float(k4.y);
        p2 += __half2float(q4.z) * __half2float(k4.z);
        p3 += __half2float(q4.w) * __half2float(k4.w);
    }
#pragma unroll
    for (int off = 8; off > 0; off >>= 1) {
        p0 += __shfl_down(p0, off, 16);
        p1 += __shfl_down(p1, off, 16);
        p2 += __shfl_down(p2, off, 16);
        p3 += __shfl_down(p3, off, 16);
    }
    if (lane == 0) {
        float4 at = *(const float4*)(attr_s + (size_t)ii * 4);
        const float4* qw = (const float4*)(qwe + (size_t)dst * 16);
        float4 w0 = qw[0], w1 = qw[1], w2 = qw[2], w3 = qw[3];
        p0 += at.x * w0.x + at.y * w1.x + at.z * w2.x + at.w * w3.x;
        p1 += at.x * w0.y + at.y * w1.y + at.z * w2.y + at.w * w3.y;
        p2 += at.x * w0.z + at.y * w1.z + at.z * w2.z + at.w * w3.z;
        p3 += at.x * w0.w + at.y * w1.w + at.z * w2.w + at.w * w3.w;
        float4 o;
        o.x = __expf(p0 * SCALE_);
        o.y = __expf(p1 * SCALE_);
        o.z = __expf(p2 * SCALE_);
        o.w = __expf(p3 * SCALE_);
        *(float4*)(alpha + (size_t)ii * 4) = o;
    }
}

// ---------------- node gather: msg + We-term + beta gate + relu -------------
__global__ void k_node_msg(const int* __restrict__ rowp, const int* __restrict__ srcs,
                           const float* __restrict__ alpha, const float* __restrict__ attr_s,
                           const __half* __restrict__ vh,
                           const float* __restrict__ We, const float* __restrict__ xr,
                           const float* __restrict__ Wb, float* __restrict__ h) {
    __shared__ float WeL[1024];
    __shared__ float WbL[192];
    int tid = threadIdx.x;
    for (int t = tid; t < 1024; t += 256) WeL[t] = We[t];
    if (tid < 192) WbL[tid] = Wb[tid];
    __syncthreads();

    int dst = blockIdx.x * 4 + (tid >> 6);
    if (dst >= N_N) return;
    int lane = tid & 63;
    int rp0 = rowp[dst], rp1 = rowp[dst + 1];

    float n0 = 0.f, n1 = 0.f, n2 = 0.f, n3 = 0.f;
    float d0 = 0.f, d1 = 0.f, d2 = 0.f, d3 = 0.f;
    float t00=0,t01=0,t02=0,t03=0, t10=0,t11=0,t12=0,t13=0;
    float t20=0,t21=0,t22=0,t23=0, t30=0,t31=0,t32=0,t33=0;

    int ii = rp0;
    for (; ii + 1 < rp1; ii += 2) {
        int sA = srcs[ii], sB = srcs[ii + 1];
        float4 aA = *(const float4*)(alpha + (size_t)ii * 4);
        float4 aB = *(const float4*)(alpha + (size_t)(ii + 1) * 4);
        float4 tA = *(const float4*)(attr_s + (size_t)ii * 4);
        float4 tB = *(const float4*)(attr_s + (size_t)(ii + 1) * 4);
        h4v vA = *(const h4v*)(vh + (size_t)sA * 256 + lane * 4);
        h4v vB = *(const h4v*)(vh + (size_t)sB * 256 + lane * 4);
        d0 += aA.x; d1 += aA.y; d2 += aA.z; d3 += aA.w;
        n0 += aA.x * __half2float(vA.x);
        n1 += aA.y * __half2float(vA.y);
        n2 += aA.z * __half2float(vA.z);
        n3 += aA.w * __half2float(vA.w);
        t00 += tA.x * aA.x; t01 += tA.x * aA.y; t02 += tA.x * aA.z; t03 += tA.x * aA.w;
        t10 += tA.y * aA.x; t11 += tA.y * aA.y; t12 += tA.y * aA.z; t13 += tA.y * aA.w;
        t20 += tA.z * aA.x; t21 += tA.z * aA.y; t22 += tA.z * aA.z; t23 += tA.z * aA.w;
        t30 += tA.w * aA.x; t31 += tA.w * aA.y; t32 += tA.w * aA.z; t33 += tA.w * aA.w;
        d0 += aB.x; d1 += aB.y; d2 += aB.z; d3 += aB.w;
        n0 += aB.x * __half2float(vB.x);
        n1 += aB.y * __half2float(vB.y);
        n2 += aB.z * __half2float(vB.z);
        n3 += aB.w * __half2float(vB.w);
        t00 += tB.x * aB.x; t01 += tB.x * aB.y; t02 += tB.x * aB.z; t03 += tB.x * aB.w;
        t10 += tB.y * aB.x; t11 += tB.y * aB.y; t12 += tB.y * aB.z; t13 += tB.y * aB.w;
        t20 += tB.z * aB.x; t21 += tB.z * aB.y; t22 += tB.z * aB.z; t23 += tB.z * aB.w;
        t30 += tB.w * aB.x; t31 += tB.w * aB.y; t32 += tB.w * aB.z; t33 += tB.w * aB.w;
    }
    if (ii < rp1) {
        int sA = srcs[ii];
        float4 aA = *(const float4*)(alpha + (size_t)ii * 4);
        float4 tA = *(const float4*)(attr_s + (size_t)ii * 4);
        h4v vA = *(const h4v*)(vh + (size_t)sA * 256 + lane * 4);
        d0 += aA.x; d1 += aA.y; d2 += aA.z; d3 += aA.w;
        n0 += aA.x * __half2float(vA.x);
        n1 += aA.y * __half2float(vA.y);
        n2 += aA.z * __half2float(vA.z);
        n3 += aA.w * __half2float(vA.w);
        t00 += tA.x * aA.x; t01 += tA.x * aA.y; t02 += tA.x * aA.z; t03 += tA.x * aA.w;
        t10 += tA.y * aA.x; t11 += tA.y * aA.y; t12 += tA.y * aA.z; t13 += tA.y * aA.w;
        t20 += tA.z * aA.x; t21 += tA.z * aA.y; t22 += tA.z * aA.z; t23 += tA.z * aA.w;
        t30 += tA.w * aA.x; t31 += tA.w * aA.y; t32 += tA.w * aA.z; t33 += tA.w * aA.w;
    }
    float i0 = 1.0f / (d0 + 1e-16f), i1 = 1.0f / (d1 + 1e-16f);
    float i2 = 1.0f / (d2 + 1e-16f), i3 = 1.0f / (d3 + 1e-16f);
    float ev0 = t00 * WeL[lane]       + t10 * WeL[256 + lane]       + t20 * WeL[512 + lane]       + t30 * WeL[768 + lane];
    float ev1 = t01 * WeL[64 + lane]  + t11 * WeL[256 + 64 + lane]  + t21 * WeL[512 + 64 + lane]  + t31 * WeL[768 + 64 + lane];
    float ev2 = t02 * WeL[128 + lane] + t12 * WeL[256 + 128 + lane] + t22 * WeL[512 + 128 + lane] + t32 * WeL[768 + 128 + lane];
    float ev3 = t03 * WeL[192 + lane] + t13 * WeL[256 + 192 + lane] + t23 * WeL[512 + 192 + lane] + t33 * WeL[768 + 192 + lane];
    float o = 0.25f * ((n0 + ev0) * i0 + (n1 + ev1) * i1 + (n2 + ev2) * i2 + (n3 + ev3) * i3);

    float x = xr[(size_t)dst * 64 + lane];
    float p = o * WbL[lane] + x * WbL[64 + lane] + (o - x) * WbL[128 + lane];
#pragma unroll
    for (int off = 32; off > 0; off >>= 1) p += __shfl_down(p, off);
    float s = __shfl(p, 0);
    float beta = sigmoidf_(s);
    float val = beta * x + (1.0f - beta) * o;
    h[(size_t)dst * 64 + lane] = fmaxf(val, 0.0f);
}

// ---------------- batchnorm stats (apply fused into next k_proj) ------------
__global__ void k_bn_stats(const float* __restrict__ h, float* __restrict__ bnst) {
    int c = threadIdx.x & 63, g = threadIdx.x >> 6;
    float s = 0.0f, s2 = 0.0f;
    for (int i = blockIdx.x * 4 + g; i < N_N; i += gridDim.x * 4) {
        float v = h[i * 64 + c];
        s += v; s2 += v * v;
    }
    atomicAdd(&bnst[c], s);
    atomicAdd(&bnst[64 + c], s2);
}

// ---------------- set2set (qstar built inline from hl/rnum/denB) ------------
__global__ void k_s2s_init(float* __restrict__ hl, float* __restrict__ cl,
                           float* __restrict__ rnum, float* __restrict__ denB) {
    int t = blockIdx.x * 256 + threadIdx.x;
    if (t < B_B * D_D) { hl[t] = 0.0f; cl[t] = 0.0f; rnum[t] = 0.0f; }
    if (t < B_B) denB[t] = 0.0f;
}

__global__ void k_lstm(float* __restrict__ hl, float* __restrict__ cl,
                       const float* __restrict__ rnum, const float* __restrict__ denB,
                       const float* __restrict__ Wih, const float* __restrict__ Whh,
                       const float* __restrict__ bih, const float* __restrict__ bhh,
                       float* __restrict__ mB, float* __restrict__ denBo,
                       float* __restrict__ rnumo) {
    int b = blockIdx.x, tid = threadIdx.x;
    __shared__ float qs[128], hs[64], gates[256];
    if (tid < 64) {
        float hv = hl[b * 64 + tid];
        qs[tid] = hv; hs[tid] = hv;
    } else if (tid < 128) {
        qs[tid] = rnum[b * 64 + (tid - 64)] / (denB[b] + 1e-16f);
    }
    __syncthreads();
    float acc = bih[tid] + bhh[tid];
    for (int j = 0; j < 128; j++) acc += qs[j] * Wih[tid * 128 + j];
    for (int j = 0; j < 64; j++) acc += hs[j] * Whh[tid * 64 + j];
    gates[tid] = acc;
    __syncthreads();
    if (tid < 64) {
        float ig = sigmoidf_(gates[tid]);
        float fg = sigmoidf_(gates[64 + tid]);
        float gg = tanhf(gates[128 + tid]);
        float og = sigmoidf_(gates[192 + tid]);
        float c = fg * cl[b * 64 + tid] + ig * gg;
        float hh = og * tanhf(c);
        cl[b * 64 + tid] = c;
        hl[b * 64 + tid] = hh;
        rnumo[b * 64 + tid] = 0.0f;
    }
    if (tid == 0) { mB[b] = -INFINITY; denBo[b] = 0.0f; }
}

__global__ void k_s2s_dot(const float* __restrict__ h, const float* __restrict__ hl,
                          const int* __restrict__ batch, float* __restrict__ eN,
                          float* __restrict__ mB) {
    int i = blockIdx.x * 4 + (threadIdx.x >> 6);
    if (i >= N_N) return;
    int lane = threadIdx.x & 63;
    int b = batch[i];
    float p = h[i * 64 + lane] * hl[b * 64 + lane];
#pragma unroll
    for (int off = 32; off > 0; off >>= 1) p += __shfl_down(p, off);
    if (lane == 0) { eN[i] = p; atomicMaxF(&mB[b], p); }
}

// exp + den + r-numerator in one pass
__global__ void k_s2s_expnum(const float* __restrict__ h, const int* __restrict__ batch,
                             const float* __restrict__ eN, const float* __restrict__ mB,
                             float* __restrict__ denB, float* __restrict__ rnum) {
    int i = blockIdx.x * 4 + (threadIdx.x >> 6);
    if (i >= N_N) return;
    int lane = threadIdx.x & 63;
    int b = batch[i];
    float ex = expf(eN[i] - mB[b]);
    if (lane == 0) atomicAdd(&denB[b], ex);
    atomicAdd(&rnum[b * 64 + lane], ex * h[i * 64 + lane]);
}

// ---------------- heads + reparameterization --------------------------------
__global__ void k_final(const float* __restrict__ hl, const float* __restrict__ rnum,
                        const float* __restrict__ denB,
                        const float* __restrict__ Wmu, const float* __restrict__ bmu,
                        const float* __restrict__ Wlv, const float* __restrict__ blv,
                        const float* __restrict__ epsb,
                        float* __restrict__ outp) {
    int b = blockIdx.x, tid = threadIdx.x;  // 128 threads
    __shared__ float qs[128];
    qs[tid] = (tid < 64) ? hl[b * 64 + tid]
                         : rnum[b * 64 + (tid - 64)] / (denB[b] + 1e-16f);
    __syncthreads();
    float mu = bmu[tid], lv = blv[tid];
    for (int j = 0; j < 128; j++) {
        float qv = qs[j];
        mu += qv * Wmu[j * 128 + tid];
        lv += qv * Wlv[j * 128 + tid];
    }
    int idx = b * 128 + tid;
    float z = epsb[idx] * expf(0.5f * lv) + mu;
    outp[idx] = z;
    outp[32768 + idx] = mu;
    outp[65536 + idx] = lv;
}

// ---------------- host ------------------------------------------------------
extern "C" void kernel_launch(void* const* d_in, const int* in_sizes, int n_in,
                              void* d_out, int out_size, void* d_ws, size_t ws_size,
                              hipStream_t stream) {
    const float* x     = (const float*)d_in[0];
    const float* eattr = (const float*)d_in[1];
    const int*   ei    = (const int*)d_in[2];
    const int*   batch = (const int*)d_in[3];
    const float* Wq = (const float*)d_in[4],  *bq = (const float*)d_in[5];
    const float* Wk = (const float*)d_in[6],  *bk = (const float*)d_in[7];
    const float* Wv = (const float*)d_in[8],  *bv = (const float*)d_in[9];
    const float* We = (const float*)d_in[10];
    const float* Ws = (const float*)d_in[11], *bs = (const float*)d_in[12];
    const float* Wb = (const float*)d_in[13];
    const float* bng = (const float*)d_in[14], *bnb = (const float*)d_in[15];
    const float* Wih = (const float*)d_in[16], *Whh = (const float*)d_in[17];
    const float* bih = (const float*)d_in[18], *bhh = (const float*)d_in[19];
    const float* Wmu = (const float*)d_in[20], *bmu = (const float*)d_in[21];
    const float* Wlv = (const float*)d_in[22], *blv = (const float*)d_in[23];
    float* fout = (float*)d_out;

    float* ws    = (float*)d_ws;
    float* h     = ws;  ws += N_N * D_D;
    __half* qh   = (__half*)ws; ws += N_N * 128;   // N*256 halves
    __half* kh   = (__half*)ws; ws += N_N * 128;
    __half* vh   = (__half*)ws; ws += N_N * 128;
    float* xr    = ws;  ws += N_N * D_D;
    float* qwe   = ws;  ws += N_N * 16;
    float* alpha = ws;  ws += E_E * H_H;
    float* bnst  = ws;  ws += 512;                 // 4 layers x 128
    // CSR: deg|cnt contiguous (one memset), rowp, srcs, dsts, attr_s
    int* deg   = (int*)ws; ws += N_N;
    int* cnt   = (int*)ws; ws += N_N;
    int* rowp  = (int*)ws; ws += N_N + 1;
    int* srcs  = (int*)ws; ws += E_E;
    int* dsts  = (int*)ws; ws += E_E;
    float* attr_s = ws; ws += E_E * 4;
    float* hl    = ws;  ws += B_B * D_D;
    float* cl    = ws;  ws += B_B * D_D;
    float* rnum  = ws;  ws += B_B * D_D;
    float* eN    = ws;  ws += N_N;
    float* mB    = ws;  ws += B_B;
    float* denB  = ws;  ws += B_B;
    float* epsb  = ws;  ws += 32768;

    k_eps<<<128, 256, 0, stream>>>(epsb);
    hipMemsetAsync(bnst, 0, 512 * 4, stream);
    hipMemsetAsync(deg, 0, (size_t)2 * N_N * 4, stream);   // deg + cnt
    k_hist<<<(E_E + 255) / 256, 256, 0, stream>>>(ei, deg);
    k_scan<<<1, 1024, 0, stream>>>(deg, rowp);
    k_scatter<<<(E_E + 255) / 256, 256, 0, stream>>>(ei, eattr, rowp, cnt, srcs, dsts, attr_s);

    const float* hin = x;
    for (int l = 0; l < 4; l++) {
        k_proj<<<N_N / 8, 256, 0, stream>>>(hin,
            Wq + l * 64 * 256, bq + l * 256,
            Wk + l * 64 * 256, bk + l * 256,
            Wv + l * 64 * 256, bv + l * 256,
            Ws + l * 64 * 64, bs + l * 64,
            bnst + (l > 0 ? (l - 1) * 128 : 0),
            bng + (l > 0 ? (l - 1) * 64 : 0), bnb + (l > 0 ? (l - 1) * 64 : 0),
            (l > 0) ? 1 : 0,
            qh, kh, vh, xr);
        k_qwe<<<(N_N * 16 + 255) / 256, 256, 0, stream>>>(qh, We + l * 1024, qwe);
        k_edge_alpha<<<E_E / 16, 256, 0, stream>>>(qh, kh, attr_s, qwe, srcs, dsts, alpha);
        k_node_msg<<<(N_N + 3) / 4, 256, 0, stream>>>(rowp, srcs, alpha, attr_s, vh,
                                                      We + l * 1024, xr, Wb + l * 192, h);
        if (l < 3) {
            k_bn_stats<<<256, 256, 0, stream>>>(h, bnst + l * 128);
        }
        hin = h;
    }

    k_s2s_init<<<(B_B * D_D + 255) / 256, 256, 0, stream>>>(hl, cl, rnum, denB);
    for (int s = 0; s < 4; s++) {
        k_lstm<<<B_B, 256, 0, stream>>>(hl, cl, rnum, denB, Wih, Whh, bih, bhh, mB, denB, rnum);
        k_s2s_dot<<<(N_N + 3) / 4, 256, 0, stream>>>(h, hl, batch, eN, mB);
        k_s2s_expnum<<<(N_N + 3) / 4, 256, 0, stream>>>(h, batch, eN, mB, denB, rnum);
    }
    k_final<<<B_B, 128, 0, stream>>>(hl, rnum, denB, Wmu, bmu, Wlv, blv, epsb, fout);
}

// Round 28
// 767.923 us; speedup vs baseline: 1.4459x; 1.4459x over previous
//
#include <hip/hip_runtime.h>
#include <hip/hip_bf16.h>
#include <hip/hip_fp16.h>
#include <math.h>
#include <stdint.h>

#define N_N 20000
#define E_E 320000
#define B_B 256
#define D_D 64
#define H_H 4
#define HC  256
#define SCALE_ 0.125f   // 1/sqrt(64)

struct h4v { __half x, y, z, w; };

__device__ __forceinline__ float sigmoidf_(float x) { return 1.0f / (1.0f + expf(-x)); }

// ---------------- Threefry2x32 (KAT-verified r5) ----------------------------
__device__ __forceinline__ void tf_round(uint32_t& x0, uint32_t& x1, int R) {
    x0 += x1; x1 = (x1 << R) | (x1 >> (32 - R)); x1 ^= x0;
}
__device__ void threefry2x32(uint32_t k0, uint32_t k1, uint32_t c0, uint32_t c1,
                             uint32_t& o0, uint32_t& o1) {
    const int rot[8] = {13, 15, 26, 6, 17, 29, 16, 24};
    uint32_t ks[3] = {k0, k1, k0 ^ k1 ^ 0x1BD11BDAu};
    uint32_t x0 = c0 + ks[0], x1 = c1 + ks[1];
#pragma unroll
    for (int g = 0; g < 5; ++g) {
        const int base = (g & 1) ? 4 : 0;
        tf_round(x0, x1, rot[base + 0]); tf_round(x0, x1, rot[base + 1]);
        tf_round(x0, x1, rot[base + 2]); tf_round(x0, x1, rot[base + 3]);
        x0 += ks[(g + 1) % 3]; x1 += ks[(g + 2) % 3] + (uint32_t)(g + 1);
    }
    o0 = x0; o1 = x1;
}

__device__ __forceinline__ float jax_n32(uint32_t bits) {
    float f = __uint_as_float((bits >> 9) | 0x3f800000u) - 1.0f;
    const float lo = -0x1.fffffep-1f;
    float u = 2.0f * f + lo;
    u = fmaxf(lo, u);
    return 1.41421356237f * erfinvf(u);
}

// eps: jax partitionable 32-bit = XOR fold of threefry output pair (r20 PASS)
__global__ void k_eps(float* __restrict__ eps) {
    int i = blockIdx.x * 256 + threadIdx.x;
    if (i >= 32768) return;
    uint32_t o0, o1;
    threefry2x32(0u, 42u, 0u, (uint32_t)i, o0, o1);
    eps[i] = jax_n32(o0 ^ o1);
}

// ---------------- CSR build (once; ei/eattr are layer-invariant) ------------
__global__ void k_hist(const int* __restrict__ ei, int* __restrict__ deg) {
    int e = blockIdx.x * 256 + threadIdx.x;
    if (e < E_E) atomicAdd(&deg[ei[E_E + e]], 1);
}

__global__ void k_scan(const int* __restrict__ deg, int* __restrict__ rowp) {
    __shared__ int part[1024];
    int t = threadIdx.x;
    int base = t * 20;
    int loc[20]; int s = 0;
#pragma unroll
    for (int i = 0; i < 20; i++) {
        int idx = base + i;
        int v = (idx < N_N) ? deg[idx] : 0;
        loc[i] = s; s += v;
    }
    part[t] = s; __syncthreads();
    for (int off = 1; off < 1024; off <<= 1) {
        int v = (t >= off) ? part[t - off] : 0;
        __syncthreads();
        part[t] += v;
        __syncthreads();
    }
    int excl = (t == 0) ? 0 : part[t - 1];
#pragma unroll
    for (int i = 0; i < 20; i++) {
        int idx = base + i;
        if (idx < N_N) rowp[idx] = excl + loc[i];
    }
    if (t == 1023) rowp[N_N] = part[1023];
}

// scatter dst-sorted copies: srcs, dsts, attr_s
__global__ void k_scatter(const int* __restrict__ ei, const float* __restrict__ eattr,
                          const int* __restrict__ rowp, int* __restrict__ cnt,
                          int* __restrict__ srcs, int* __restrict__ dsts,
                          float* __restrict__ attr_s) {
    int e = blockIdx.x * 256 + threadIdx.x;
    if (e >= E_E) return;
    int d = ei[E_E + e];
    int p = atomicAdd(&cnt[d], 1);
    int pos = rowp[d] + p;
    srcs[pos] = ei[e];
    dsts[pos] = d;
    float4 at = *(const float4*)(eattr + (size_t)e * 4);
    *(float4*)(attr_s + (size_t)pos * 4) = at;
}

// ---------------- batch CSR (once; batch sorted) ----------------------------
__global__ void k_bhist(const int* __restrict__ batch, int* __restrict__ bdeg) {
    int i = blockIdx.x * 256 + threadIdx.x;
    if (i < N_N) atomicAdd(&bdeg[batch[i]], 1);
}
__global__ void k_bscan(const int* __restrict__ bdeg, int* __restrict__ gstart) {
    // single wave of 64: serial scan by lane 0 (256 entries, trivial)
    if (threadIdx.x == 0) {
        int s = 0;
        for (int b = 0; b < B_B; b++) { gstart[b] = s; s += bdeg[b]; }
        gstart[B_B] = s;
    }
}

// ---------------- fused projection (+BN of previous layer) ------------------
__global__ void k_proj(const float* __restrict__ hin,
                       const float* __restrict__ Wq, const float* __restrict__ bq,
                       const float* __restrict__ Wk, const float* __restrict__ bk,
                       const float* __restrict__ Wv, const float* __restrict__ bv,
                       const float* __restrict__ Ws, const float* __restrict__ bs,
                       const float* __restrict__ bnstPrev,
                       const float* __restrict__ gam, const float* __restrict__ bet,
                       int useBN,
                       __half* __restrict__ qh, __half* __restrict__ kh,
                       __half* __restrict__ vh, float* __restrict__ xr) {
    __shared__ float hs[64][8];   // [d][row]
    const int i0 = blockIdx.x * 8;
    const int tid = threadIdx.x;
    for (int t = tid; t < 8 * 64; t += 256) {
        int r = t >> 6, d = t & 63;
        float v = hin[i0 * 64 + t];
        if (useBN) {
            float mu = bnstPrev[d] * (1.0f / N_N);
            float var = bnstPrev[64 + d] * (1.0f / N_N) - mu * mu;
            v = gam[d] * (v - mu) * rsqrtf(var + 1e-5f) + bet[d];
        }
        hs[d][r] = v;
    }
    __syncthreads();
    const int c = tid;
    const int co = (c & 63) * 4 + (c >> 6);   // transposed slot
    const bool doSkip = (c < 64);
    float aq[8], ak[8], av[8], as_[8];
    {
        float b0 = bq[c], b1 = bk[c], b2 = bv[c];
        float b3 = doSkip ? bs[c] : 0.0f;
#pragma unroll
        for (int r = 0; r < 8; r++) { aq[r] = b0; ak[r] = b1; av[r] = b2; as_[r] = b3; }
    }
    for (int d = 0; d < 64; d++) {
        float wq = Wq[d * 256 + c];
        float wk = Wk[d * 256 + c];
        float wv = Wv[d * 256 + c];
        float wsv = doSkip ? Ws[d * 64 + c] : 0.0f;
        const float4* hp = (const float4*)(&hs[d][0]);
        float4 hA = hp[0], hB = hp[1];
        float hr[8] = {hA.x, hA.y, hA.z, hA.w, hB.x, hB.y, hB.z, hB.w};
#pragma unroll
        for (int r = 0; r < 8; r++) {
            float hv = hr[r];
            aq[r] += hv * wq;
            ak[r] += hv * wk;
            av[r] += hv * wv;
            as_[r] += hv * wsv;
        }
    }
#pragma unroll
    for (int r = 0; r < 8; r++) {
        qh[(size_t)(i0 + r) * 256 + co] = __float2half(aq[r]);
        kh[(size_t)(i0 + r) * 256 + co] = __float2half(ak[r]);
        vh[(size_t)(i0 + r) * 256 + co] = __float2half(av[r]);
    }
    if (doSkip) {
#pragma unroll
        for (int r = 0; r < 8; r++) xr[(size_t)(i0 + r) * 64 + c] = as_[r];
    }
}

// ---------------- qwe[n][j*4+h] = sum_d q[n][h*64+d] * We[j][h*64+d] --------
__global__ void k_qwe(const __half* __restrict__ qh, const float* __restrict__ We,
                      float* __restrict__ qwe) {
    int t = blockIdx.x * 256 + threadIdx.x;
    if (t >= N_N * 16) return;
    int n = t >> 4, j = (t >> 2) & 3, h = t & 3;
    const __half* qp = qh + (size_t)n * 256 + h;
    const float* wp = We + j * 256 + h * 64;
    float s = 0.0f;
#pragma unroll 8
    for (int d = 0; d < 64; d++)
        s += __half2float(qp[d * 4]) * wp[d];
    qwe[t] = s;
}

// ---------------- edge pass (CSR order): qk dot + qwe term ------------------
__global__ void k_edge_alpha(const __half* __restrict__ qh, const __half* __restrict__ kh,
                             const float* __restrict__ attr_s, const float* __restrict__ qwe,
                             const int* __restrict__ srcs, const int* __restrict__ dsts,
                             float* __restrict__ alpha) {
    int tid = threadIdx.x;
    int ii = blockIdx.x * 16 + (tid >> 4);
    if (ii >= E_E) return;
    int lane = tid & 15;
    int src = srcs[ii], dst = dsts[ii];
    const h4v* qp = (const h4v*)(qh + (size_t)dst * 256 + lane * 16);
    const h4v* kp = (const h4v*)(kh + (size_t)src * 256 + lane * 16);
    float p0 = 0.0f, p1 = 0.0f, p2 = 0.0f, p3 = 0.0f;
#pragma unroll
    for (int i = 0; i < 4; i++) {
        h4v q4 = qp[i], k4 = kp[i];
        p0 += __half2float(q4.x) * __half2float(k4.x);
        p1 += __half2float(q4.y) * __half2float(k4.y);
        p2 += __half2float(q4.z) * __half2float(k4.z);
        p3 += __half2float(q4.w) * __half2float(k4.w);
    }
#pragma unroll
    for (int off = 8; off > 0; off >>= 1) {
        p0 += __shfl_down(p0, off, 16);
        p1 += __shfl_down(p1, off, 16);
        p2 += __shfl_down(p2, off, 16);
        p3 += __shfl_down(p3, off, 16);
    }
    if (lane == 0) {
        float4 at = *(const float4*)(attr_s + (size_t)ii * 4);
        const float4* qw = (const float4*)(qwe + (size_t)dst * 16);
        float4 w0 = qw[0], w1 = qw[1], w2 = qw[2], w3 = qw[3];
        p0 += at.x * w0.x + at.y * w1.x + at.z * w2.x + at.w * w3.x;
        p1 += at.x * w0.y + at.y * w1.y + at.z * w2.y + at.w * w3.y;
        p2 += at.x * w0.z + at.y * w1.z + at.z * w2.z + at.w * w3.z;
        p3 += at.x * w0.w + at.y * w1.w + at.z * w2.w + at.w * w3.w;
        float4 o;
        o.x = __expf(p0 * SCALE_);
        o.y = __expf(p1 * SCALE_);
        o.z = __expf(p2 * SCALE_);
        o.w = __expf(p3 * SCALE_);
        *(float4*)(alpha + (size_t)ii * 4) = o;
    }
}

// ---------------- node gather: msg + We-term + beta gate + relu -------------
__global__ void k_node_msg(const int* __restrict__ rowp, const int* __restrict__ srcs,
                           const float* __restrict__ alpha, const float* __restrict__ attr_s,
                           const __half* __restrict__ vh,
                           const float* __restrict__ We, const float* __restrict__ xr,
                           const float* __restrict__ Wb, float* __restrict__ h) {
    __shared__ float WeL[1024];
    __shared__ float WbL[192];
    int tid = threadIdx.x;
    for (int t = tid; t < 1024; t += 256) WeL[t] = We[t];
    if (tid < 192) WbL[tid] = Wb[tid];
    __syncthreads();

    int dst = blockIdx.x * 4 + (tid >> 6);
    if (dst >= N_N) return;
    int lane = tid & 63;
    int rp0 = rowp[dst], rp1 = rowp[dst + 1];

    float n0 = 0.f, n1 = 0.f, n2 = 0.f, n3 = 0.f;
    float d0 = 0.f, d1 = 0.f, d2 = 0.f, d3 = 0.f;
    float t00=0,t01=0,t02=0,t03=0, t10=0,t11=0,t12=0,t13=0;
    float t20=0,t21=0,t22=0,t23=0, t30=0,t31=0,t32=0,t33=0;

    int ii = rp0;
    for (; ii + 1 < rp1; ii += 2) {
        int sA = srcs[ii], sB = srcs[ii + 1];
        float4 aA = *(const float4*)(alpha + (size_t)ii * 4);
        float4 aB = *(const float4*)(alpha + (size_t)(ii + 1) * 4);
        float4 tA = *(const float4*)(attr_s + (size_t)ii * 4);
        float4 tB = *(const float4*)(attr_s + (size_t)(ii + 1) * 4);
        h4v vA = *(const h4v*)(vh + (size_t)sA * 256 + lane * 4);
        h4v vB = *(const h4v*)(vh + (size_t)sB * 256 + lane * 4);
        d0 += aA.x; d1 += aA.y; d2 += aA.z; d3 += aA.w;
        n0 += aA.x * __half2float(vA.x);
        n1 += aA.y * __half2float(vA.y);
        n2 += aA.z * __half2float(vA.z);
        n3 += aA.w * __half2float(vA.w);
        t00 += tA.x * aA.x; t01 += tA.x * aA.y; t02 += tA.x * aA.z; t03 += tA.x * aA.w;
        t10 += tA.y * aA.x; t11 += tA.y * aA.y; t12 += tA.y * aA.z; t13 += tA.y * aA.w;
        t20 += tA.z * aA.x; t21 += tA.z * aA.y; t22 += tA.z * aA.z; t23 += tA.z * aA.w;
        t30 += tA.w * aA.x; t31 += tA.w * aA.y; t32 += tA.w * aA.z; t33 += tA.w * aA.w;
        d0 += aB.x; d1 += aB.y; d2 += aB.z; d3 += aB.w;
        n0 += aB.x * __half2float(vB.x);
        n1 += aB.y * __half2float(vB.y);
        n2 += aB.z * __half2float(vB.z);
        n3 += aB.w * __half2float(vB.w);
        t00 += tB.x * aB.x; t01 += tB.x * aB.y; t02 += tB.x * aB.z; t03 += tB.x * aB.w;
        t10 += tB.y * aB.x; t11 += tB.y * aB.y; t12 += tB.y * aB.z; t13 += tB.y * aB.w;
        t20 += tB.z * aB.x; t21 += tB.z * aB.y; t22 += tB.z * aB.z; t23 += tB.z * aB.w;
        t30 += tB.w * aB.x; t31 += tB.w * aB.y; t32 += tB.w * aB.z; t33 += tB.w * aB.w;
    }
    if (ii < rp1) {
        int sA = srcs[ii];
        float4 aA = *(const float4*)(alpha + (size_t)ii * 4);
        float4 tA = *(const float4*)(attr_s + (size_t)ii * 4);
        h4v vA = *(const h4v*)(vh + (size_t)sA * 256 + lane * 4);
        d0 += aA.x; d1 += aA.y; d2 += aA.z; d3 += aA.w;
        n0 += aA.x * __half2float(vA.x);
        n1 += aA.y * __half2float(vA.y);
        n2 += aA.z * __half2float(vA.z);
        n3 += aA.w * __half2float(vA.w);
        t00 += tA.x * aA.x; t01 += tA.x * aA.y; t02 += tA.x * aA.z; t03 += tA.x * aA.w;
        t10 += tA.y * aA.x; t11 += tA.y * aA.y; t12 += tA.y * aA.z; t13 += tA.y * aA.w;
        t20 += tA.z * aA.x; t21 += tA.z * aA.y; t22 += tA.z * aA.z; t23 += tA.z * aA.w;
        t30 += tA.w * aA.x; t31 += tA.w * aA.y; t32 += tA.w * aA.z; t33 += tA.w * aA.w;
    }
    float i0 = 1.0f / (d0 + 1e-16f), i1 = 1.0f / (d1 + 1e-16f);
    float i2 = 1.0f / (d2 + 1e-16f), i3 = 1.0f / (d3 + 1e-16f);
    float ev0 = t00 * WeL[lane]       + t10 * WeL[256 + lane]       + t20 * WeL[512 + lane]       + t30 * WeL[768 + lane];
    float ev1 = t01 * WeL[64 + lane]  + t11 * WeL[256 + 64 + lane]  + t21 * WeL[512 + 64 + lane]  + t31 * WeL[768 + 64 + lane];
    float ev2 = t02 * WeL[128 + lane] + t12 * WeL[256 + 128 + lane] + t22 * WeL[512 + 128 + lane] + t32 * WeL[768 + 128 + lane];
    float ev3 = t03 * WeL[192 + lane] + t13 * WeL[256 + 192 + lane] + t23 * WeL[512 + 192 + lane] + t33 * WeL[768 + 192 + lane];
    float o = 0.25f * ((n0 + ev0) * i0 + (n1 + ev1) * i1 + (n2 + ev2) * i2 + (n3 + ev3) * i3);

    float x = xr[(size_t)dst * 64 + lane];
    float p = o * WbL[lane] + x * WbL[64 + lane] + (o - x) * WbL[128 + lane];
#pragma unroll
    for (int off = 32; off > 0; off >>= 1) p += __shfl_down(p, off);
    float s = __shfl(p, 0);
    float beta = sigmoidf_(s);
    float val = beta * x + (1.0f - beta) * o;
    h[(size_t)dst * 64 + lane] = fmaxf(val, 0.0f);
}

// ---------------- batchnorm stats (apply fused into next k_proj) ------------
__global__ void k_bn_stats(const float* __restrict__ h, float* __restrict__ bnst) {
    int c = threadIdx.x & 63, g = threadIdx.x >> 6;
    float s = 0.0f, s2 = 0.0f;
    for (int i = blockIdx.x * 4 + g; i < N_N; i += gridDim.x * 4) {
        float v = h[i * 64 + c];
        s += v; s2 += v * v;
    }
    atomicAdd(&bnst[c], s);
    atomicAdd(&bnst[64 + c], s2);
}

// ---------------- set2set (qstar inline; graph-local softmax, no atomics) ---
__global__ void k_s2s_init(float* __restrict__ hl, float* __restrict__ cl,
                           float* __restrict__ rnum, float* __restrict__ denB) {
    int t = blockIdx.x * 256 + threadIdx.x;
    if (t < B_B * D_D) { hl[t] = 0.0f; cl[t] = 0.0f; rnum[t] = 0.0f; }
    if (t < B_B) denB[t] = 0.0f;
}

__global__ void k_lstm(float* __restrict__ hl, float* __restrict__ cl,
                       const float* __restrict__ rnum, const float* __restrict__ denB,
                       const float* __restrict__ Wih, const float* __restrict__ Whh,
                       const float* __restrict__ bih, const float* __restrict__ bhh) {
    int b = blockIdx.x, tid = threadIdx.x;
    __shared__ float qs[128], hs[64], gates[256];
    if (tid < 64) {
        float hv = hl[b * 64 + tid];
        qs[tid] = hv; hs[tid] = hv;
    } else if (tid < 128) {
        qs[tid] = rnum[b * 64 + (tid - 64)] / (denB[b] + 1e-16f);
    }
    __syncthreads();
    float acc = bih[tid] + bhh[tid];
    for (int j = 0; j < 128; j++) acc += qs[j] * Wih[tid * 128 + j];
    for (int j = 0; j < 64; j++) acc += hs[j] * Whh[tid * 64 + j];
    gates[tid] = acc;
    __syncthreads();
    if (tid < 64) {
        float ig = sigmoidf_(gates[tid]);
        float fg = sigmoidf_(gates[64 + tid]);
        float gg = tanhf(gates[128 + tid]);
        float og = sigmoidf_(gates[192 + tid]);
        float c = fg * cl[b * 64 + tid] + ig * gg;
        float hh = og * tanhf(c);
        cl[b * 64 + tid] = c;
        hl[b * 64 + tid] = hh;
    }
}

// one block (4 waves) per graph: online softmax over its node range
__global__ void k_s2s_reduce(const float* __restrict__ h, const float* __restrict__ hl,
                             const int* __restrict__ gstart,
                             float* __restrict__ rnum, float* __restrict__ denB) {
    __shared__ float mS[4], dS[4], rS[4][64];
    int b = blockIdx.x;
    int tid = threadIdx.x;
    int wv = tid >> 6, lane = tid & 63;
    int gs = gstart[b], ge = gstart[b + 1];
    float hlv = hl[b * 64 + lane];

    float m = -INFINITY, den = 0.0f, rn = 0.0f;
    for (int j = gs + wv; j < ge; j += 4) {
        float hv = h[(size_t)j * 64 + lane];
        float p = hv * hlv;
#pragma unroll
        for (int off = 32; off > 0; off >>= 1) p += __shfl_down(p, off);
        float e = __shfl(p, 0);
        float mn = fmaxf(m, e);
        float sc = __expf(m - mn);      // 0 when m = -inf
        float ee = __expf(e - mn);
        den = den * sc + ee;
        rn  = rn * sc + ee * hv;
        m = mn;
    }
    if (lane == 0) { mS[wv] = m; dS[wv] = den; }
    rS[wv][lane] = rn;
    __syncthreads();
    if (wv == 0) {
        float m0 = fmaxf(fmaxf(mS[0], mS[1]), fmaxf(mS[2], mS[3]));
        if (m0 == -INFINITY) {          // empty graph
            if (lane == 0) denB[b] = 0.0f;
            rnum[b * 64 + lane] = 0.0f;
            return;
        }
        float s0 = __expf(mS[0] - m0), s1 = __expf(mS[1] - m0);
        float s2 = __expf(mS[2] - m0), s3 = __expf(mS[3] - m0);
        float dtot = dS[0] * s0 + dS[1] * s1 + dS[2] * s2 + dS[3] * s3;
        float rtot = rS[0][lane] * s0 + rS[1][lane] * s1 + rS[2][lane] * s2 + rS[3][lane] * s3;
        if (lane == 0) denB[b] = dtot;
        rnum[b * 64 + lane] = rtot;
    }
}

// ---------------- heads + reparameterization --------------------------------
__global__ void k_final(const float* __restrict__ hl, const float* __restrict__ rnum,
                        const float* __restrict__ denB,
                        const float* __restrict__ Wmu, const float* __restrict__ bmu,
                        const float* __restrict__ Wlv, const float* __restrict__ blv,
                        const float* __restrict__ epsb,
                        float* __restrict__ outp) {
    int b = blockIdx.x, tid = threadIdx.x;  // 128 threads
    __shared__ float qs[128];
    qs[tid] = (tid < 64) ? hl[b * 64 + tid]
                         : rnum[b * 64 + (tid - 64)] / (denB[b] + 1e-16f);
    __syncthreads();
    float mu = bmu[tid], lv = blv[tid];
    for (int j = 0; j < 128; j++) {
        float qv = qs[j];
        mu += qv * Wmu[j * 128 + tid];
        lv += qv * Wlv[j * 128 + tid];
    }
    int idx = b * 128 + tid;
    float z = epsb[idx] * expf(0.5f * lv) + mu;
    outp[idx] = z;
    outp[32768 + idx] = mu;
    outp[65536 + idx] = lv;
}

// ---------------- host ------------------------------------------------------
extern "C" void kernel_launch(void* const* d_in, const int* in_sizes, int n_in,
                              void* d_out, int out_size, void* d_ws, size_t ws_size,
                              hipStream_t stream) {
    const float* x     = (const float*)d_in[0];
    const float* eattr = (const float*)d_in[1];
    const int*   ei    = (const int*)d_in[2];
    const int*   batch = (const int*)d_in[3];
    const float* Wq = (const float*)d_in[4],  *bq = (const float*)d_in[5];
    const float* Wk = (const float*)d_in[6],  *bk = (const float*)d_in[7];
    const float* Wv = (const float*)d_in[8],  *bv = (const float*)d_in[9];
    const float* We = (const float*)d_in[10];
    const float* Ws = (const float*)d_in[11], *bs = (const float*)d_in[12];
    const float* Wb = (const float*)d_in[13];
    const float* bng = (const float*)d_in[14], *bnb = (const float*)d_in[15];
    const float* Wih = (const float*)d_in[16], *Whh = (const float*)d_in[17];
    const float* bih = (const float*)d_in[18], *bhh = (const float*)d_in[19];
    const float* Wmu = (const float*)d_in[20], *bmu = (const float*)d_in[21];
    const float* Wlv = (const float*)d_in[22], *blv = (const float*)d_in[23];
    float* fout = (float*)d_out;

    float* ws    = (float*)d_ws;
    float* h     = ws;  ws += N_N * D_D;
    __half* qh   = (__half*)ws; ws += N_N * 128;
    __half* kh   = (__half*)ws; ws += N_N * 128;
    __half* vh   = (__half*)ws; ws += N_N * 128;
    float* xr    = ws;  ws += N_N * D_D;
    float* qwe   = ws;  ws += N_N * 16;
    float* alpha = ws;  ws += E_E * H_H;
    float* bnst  = ws;  ws += 512;
    // CSR + batch CSR: deg|cnt|bdeg contiguous (one memset)
    int* deg   = (int*)ws; ws += N_N;
    int* cnt   = (int*)ws; ws += N_N;
    int* bdeg  = (int*)ws; ws += B_B;
    int* rowp  = (int*)ws; ws += N_N + 1;
    int* gstart = (int*)ws; ws += B_B + 1;
    int* srcs  = (int*)ws; ws += E_E;
    int* dsts  = (int*)ws; ws += E_E;
    float* attr_s = ws; ws += E_E * 4;
    float* hl    = ws;  ws += B_B * D_D;
    float* cl    = ws;  ws += B_B * D_D;
    float* rnum  = ws;  ws += B_B * D_D;
    float* denB  = ws;  ws += B_B;
    float* epsb  = ws;  ws += 32768;

    k_eps<<<128, 256, 0, stream>>>(epsb);
    hipMemsetAsync(bnst, 0, 512 * 4, stream);
    hipMemsetAsync(deg, 0, (size_t)(2 * N_N + B_B) * 4, stream);   // deg + cnt + bdeg
    k_hist<<<(E_E + 255) / 256, 256, 0, stream>>>(ei, deg);
    k_scan<<<1, 1024, 0, stream>>>(deg, rowp);
    k_scatter<<<(E_E + 255) / 256, 256, 0, stream>>>(ei, eattr, rowp, cnt, srcs, dsts, attr_s);
    k_bhist<<<(N_N + 255) / 256, 256, 0, stream>>>(batch, bdeg);
    k_bscan<<<1, 64, 0, stream>>>(bdeg, gstart);

    const float* hin = x;
    for (int l = 0; l < 4; l++) {
        k_proj<<<N_N / 8, 256, 0, stream>>>(hin,
            Wq + l * 64 * 256, bq + l * 256,
            Wk + l * 64 * 256, bk + l * 256,
            Wv + l * 64 * 256, bv + l * 256,
            Ws + l * 64 * 64, bs + l * 64,
            bnst + (l > 0 ? (l - 1) * 128 : 0),
            bng + (l > 0 ? (l - 1) * 64 : 0), bnb + (l > 0 ? (l - 1) * 64 : 0),
            (l > 0) ? 1 : 0,
            qh, kh, vh, xr);
        k_qwe<<<(N_N * 16 + 255) / 256, 256, 0, stream>>>(qh, We + l * 1024, qwe);
        k_edge_alpha<<<E_E / 16, 256, 0, stream>>>(qh, kh, attr_s, qwe, srcs, dsts, alpha);
        k_node_msg<<<(N_N + 3) / 4, 256, 0, stream>>>(rowp, srcs, alpha, attr_s, vh,
                                                      We + l * 1024, xr, Wb + l * 192, h);
        if (l < 3) {
            k_bn_stats<<<256, 256, 0, stream>>>(h, bnst + l * 128);
        }
        hin = h;
    }

    k_s2s_init<<<(B_B * D_D + 255) / 256, 256, 0, stream>>>(hl, cl, rnum, denB);
    for (int s = 0; s < 4; s++) {
        k_lstm<<<B_B, 256, 0, stream>>>(hl, cl, rnum, denB, Wih, Whh, bih, bhh);
        k_s2s_reduce<<<B_B, 256, 0, stream>>>(h, hl, gstart, rnum, denB);
    }
    k_final<<<B_B, 128, 0, stream>>>(hl, rnum, denB, Wmu, bmu, Wlv, blv, epsb, fout);
}